// Round 1
// baseline (2019.607 us; speedup 1.0000x reference)
//
#include <hip/hip_runtime.h>

#define N_NODES 200000
#define N_EDGES 400000
#define CH 128
#define N_GRAPHS 8192
#define BN_EPS 1e-5f

#define TM 64
#define PAD 129   // 64x128 tile padded: column reads hit distinct banks

// aggr[dst] += h[src], one wave (64 lanes) per edge, float2 per lane
__global__ __launch_bounds__(256) void scatter_kernel(
    const float* __restrict__ h, const int* __restrict__ src,
    const int* __restrict__ dst, float* __restrict__ aggr)
{
    int gid = blockIdx.x * blockDim.x + threadIdx.x;
    int e = gid >> 6;
    int lane = gid & 63;
    if (e >= N_EDGES) return;
    int s = src[e];
    int d = dst[e];
    float2 v = ((const float2*)(h + (long)s * CH))[lane];
    float* ap = aggr + (long)d * CH + lane * 2;
    atomicAdd(ap, v.x);
    atomicAdd(ap + 1, v.y);
}

// Fused GIN MLP: hout = relu( relu(bn((hin+aggr) @ W1 + b1)) @ W2 + b2 )
// 64-row tile per block, 256 threads, 4x8 register tile per thread.
__global__ __launch_bounds__(256) void mlp_kernel(
    const float* __restrict__ hin, const float* __restrict__ aggr,
    const float* __restrict__ W1, const float* __restrict__ b1,
    const float* __restrict__ gamma, const float* __restrict__ beta,
    const float* __restrict__ mean, const float* __restrict__ var,
    const float* __restrict__ W2, const float* __restrict__ b2,
    float* __restrict__ hout)
{
    __shared__ float a_s[TM * PAD];
    const int tid = threadIdx.x;
    const int tx = tid & 15;   // 16 col-groups of 8
    const int ty = tid >> 4;   // 16 row-groups of 4
    const long base = (long)blockIdx.x * TM * CH;

    // stage tile: a = hin + aggr  (scalar LDS writes into padded layout)
    for (int i = tid; i < TM * CH / 4; i += 256) {
        float4 hv = ((const float4*)hin)[base / 4 + i];
        float4 av = ((const float4*)aggr)[base / 4 + i];
        int r = i >> 5;            // 32 float4 per row
        int c = (i & 31) << 2;
        float* dp = &a_s[r * PAD + c];
        dp[0] = hv.x + av.x; dp[1] = hv.y + av.y;
        dp[2] = hv.z + av.z; dp[3] = hv.w + av.w;
    }

    // fold bias+BN into per-column scale/shift for this thread's 8 columns
    float A[8], Bc[8], b2c[8];
    #pragma unroll
    for (int j = 0; j < 8; ++j) {
        int c = tx * 8 + j;
        float rs = rsqrtf(var[c] + BN_EPS);
        float sc = rs * gamma[c];
        A[j] = sc;
        Bc[j] = (b1[c] - mean[c]) * sc + beta[c];
        b2c[j] = b2[c];
    }

    __syncthreads();

    float acc[4][8];
    #pragma unroll
    for (int i = 0; i < 4; ++i)
        #pragma unroll
        for (int j = 0; j < 8; ++j) acc[i][j] = 0.f;

    // GEMM1: t = a @ W1
    for (int k = 0; k < CH; ++k) {
        float4 w0 = *(const float4*)&W1[k * CH + tx * 8];
        float4 w1v = *(const float4*)&W1[k * CH + tx * 8 + 4];
        float a0 = a_s[(ty * 4 + 0) * PAD + k];
        float a1 = a_s[(ty * 4 + 1) * PAD + k];
        float a2 = a_s[(ty * 4 + 2) * PAD + k];
        float a3 = a_s[(ty * 4 + 3) * PAD + k];
        float wv[8] = {w0.x, w0.y, w0.z, w0.w, w1v.x, w1v.y, w1v.z, w1v.w};
        float av[4] = {a0, a1, a2, a3};
        #pragma unroll
        for (int i = 0; i < 4; ++i)
            #pragma unroll
            for (int j = 0; j < 8; ++j)
                acc[i][j] = fmaf(av[i], wv[j], acc[i][j]);
    }

    __syncthreads();  // everyone done reading a_s

    // BN + ReLU, write t back into a_s
    #pragma unroll
    for (int i = 0; i < 4; ++i) {
        int r = ty * 4 + i;
        #pragma unroll
        for (int j = 0; j < 8; ++j) {
            float t = fmaf(acc[i][j], A[j], Bc[j]);
            a_s[r * PAD + tx * 8 + j] = fmaxf(t, 0.f);
        }
    }
    __syncthreads();

    #pragma unroll
    for (int i = 0; i < 4; ++i)
        #pragma unroll
        for (int j = 0; j < 8; ++j) acc[i][j] = 0.f;

    // GEMM2: out = t @ W2
    for (int k = 0; k < CH; ++k) {
        float4 w0 = *(const float4*)&W2[k * CH + tx * 8];
        float4 w1v = *(const float4*)&W2[k * CH + tx * 8 + 4];
        float a0 = a_s[(ty * 4 + 0) * PAD + k];
        float a1 = a_s[(ty * 4 + 1) * PAD + k];
        float a2 = a_s[(ty * 4 + 2) * PAD + k];
        float a3 = a_s[(ty * 4 + 3) * PAD + k];
        float wv[8] = {w0.x, w0.y, w0.z, w0.w, w1v.x, w1v.y, w1v.z, w1v.w};
        float av[4] = {a0, a1, a2, a3};
        #pragma unroll
        for (int i = 0; i < 4; ++i)
            #pragma unroll
            for (int j = 0; j < 8; ++j)
                acc[i][j] = fmaf(av[i], wv[j], acc[i][j]);
    }

    // bias + ReLU, store
    #pragma unroll
    for (int i = 0; i < 4; ++i) {
        long row = (long)blockIdx.x * TM + ty * 4 + i;
        float4 o0, o1;
        o0.x = fmaxf(acc[i][0] + b2c[0], 0.f);
        o0.y = fmaxf(acc[i][1] + b2c[1], 0.f);
        o0.z = fmaxf(acc[i][2] + b2c[2], 0.f);
        o0.w = fmaxf(acc[i][3] + b2c[3], 0.f);
        o1.x = fmaxf(acc[i][4] + b2c[4], 0.f);
        o1.y = fmaxf(acc[i][5] + b2c[5], 0.f);
        o1.z = fmaxf(acc[i][6] + b2c[6], 0.f);
        o1.w = fmaxf(acc[i][7] + b2c[7], 0.f);
        ((float4*)hout)[row * (CH / 4) + tx * 2] = o0;
        ((float4*)hout)[row * (CH / 4) + tx * 2 + 1] = o1;
    }
}

__global__ void init_out(float* __restrict__ out, const float* __restrict__ lin_b) {
    int i = blockIdx.x * blockDim.x + threadIdx.x;
    if (i < N_GRAPHS) out[i] = lin_b[0];
}

// out[batch[n]] += dot(h[n], lin_w); one wave per node
__global__ __launch_bounds__(256) void pool_kernel(
    const float* __restrict__ h, const int* __restrict__ batch,
    const float* __restrict__ lin_w, float* __restrict__ out)
{
    int gid = blockIdx.x * blockDim.x + threadIdx.x;
    int n = gid >> 6;
    int lane = gid & 63;
    if (n >= N_NODES) return;
    float2 v = ((const float2*)(h + (long)n * CH))[lane];
    float2 w = ((const float2*)lin_w)[lane];
    float s = v.x * w.x + v.y * w.y;
    #pragma unroll
    for (int off = 32; off > 0; off >>= 1) s += __shfl_down(s, off);
    if (lane == 0) atomicAdd(&out[batch[n]], s);
}

extern "C" void kernel_launch(void* const* d_in, const int* in_sizes, int n_in,
                              void* d_out, int out_size, void* d_ws, size_t ws_size,
                              hipStream_t stream) {
    const float* x     = (const float*)d_in[0];
    const int*   ei    = (const int*)d_in[1];
    const int*   batch = (const int*)d_in[2];
    const float* lin_w = (const float*)d_in[3];
    const float* lin_b = (const float*)d_in[4];
    const float* P[3][8];
    for (int l = 0; l < 3; ++l)
        for (int j = 0; j < 8; ++j)
            P[l][j] = (const float*)d_in[5 + l * 8 + j];

    float* aggr = (float*)d_ws;
    float* h0 = aggr + (size_t)N_NODES * CH;
    float* h1 = h0 + (size_t)N_NODES * CH;

    const int* src = ei;            // edge_index[0]
    const int* dst = ei + N_EDGES;  // edge_index[1]
    size_t nbytes = (size_t)N_NODES * CH * sizeof(float);

    const float* in_l[3]  = {x,  h0, h1};
    float*       out_l[3] = {h0, h1, h0};

    for (int l = 0; l < 3; ++l) {
        hipMemsetAsync(aggr, 0, nbytes, stream);
        scatter_kernel<<<(N_EDGES * 64) / 256, 256, 0, stream>>>(in_l[l], src, dst, aggr);
        mlp_kernel<<<N_NODES / TM, 256, 0, stream>>>(
            in_l[l], aggr,
            P[l][0], P[l][1], P[l][2], P[l][3], P[l][4], P[l][5], P[l][6], P[l][7],
            out_l[l]);
    }

    init_out<<<(N_GRAPHS + 255) / 256, 256, 0, stream>>>((float*)d_out, lin_b);
    pool_kernel<<<(N_NODES * 64) / 256, 256, 0, stream>>>(h0, batch, lin_w, (float*)d_out);
}

// Round 2
// 1255.392 us; speedup vs baseline: 1.6087x; 1.6087x over previous
//
#include <hip/hip_runtime.h>

#define N_NODES 200000
#define N_EDGES 400000
#define CH 128
#define N_GRAPHS 8192
#define BN_EPS 1e-5f

#define TM 64
#define PAD 129   // 64x128 tile padded: column reads hit distinct banks
#define SCAN_NB ((N_NODES + 1023) / 1024)   // 196 scan blocks

// ---------------- CSR build ----------------

__global__ __launch_bounds__(256) void count_kernel(
    const int* __restrict__ dst, int* __restrict__ deg)
{
    int e = blockIdx.x * blockDim.x + threadIdx.x;
    if (e < N_EDGES) atomicAdd(&deg[dst[e]], 1);
}

// per-block sums of 1024-elem chunks
__global__ __launch_bounds__(256) void block_sums_kernel(
    const int* __restrict__ deg, int* __restrict__ partial)
{
    __shared__ int s[256];
    int t = threadIdx.x;
    int base = blockIdx.x * 1024 + t * 4;
    int v = 0;
    #pragma unroll
    for (int j = 0; j < 4; ++j) {
        int idx = base + j;
        if (idx < N_NODES) v += deg[idx];
    }
    s[t] = v;
    __syncthreads();
    for (int off = 128; off > 0; off >>= 1) {
        if (t < off) s[t] += s[t + off];
        __syncthreads();
    }
    if (t == 0) partial[blockIdx.x] = s[0];
}

// single block: exclusive scan of SCAN_NB partial sums (serial, tiny)
__global__ void scan_partial_kernel(int* __restrict__ partial)
{
    if (threadIdx.x == 0) {
        int run = 0;
        for (int b = 0; b < SCAN_NB; ++b) {
            int v = partial[b];
            partial[b] = run;
            run += v;
        }
    }
}

// final: exclusive scan within each chunk + block offset -> row_start
__global__ __launch_bounds__(256) void scan_final_kernel(
    const int* __restrict__ deg, const int* __restrict__ partial,
    int* __restrict__ row_start)
{
    __shared__ int s[256];
    int t = threadIdx.x;
    int base = blockIdx.x * 1024 + t * 4;
    int v[4];
    int tsum = 0;
    #pragma unroll
    for (int j = 0; j < 4; ++j) {
        int idx = base + j;
        v[j] = (idx < N_NODES) ? deg[idx] : 0;
        tsum += v[j];
    }
    s[t] = tsum;
    __syncthreads();
    // Hillis-Steele inclusive scan of thread sums
    for (int off = 1; off < 256; off <<= 1) {
        int x = (t >= off) ? s[t - off] : 0;
        __syncthreads();
        s[t] += x;
        __syncthreads();
    }
    int excl = s[t] - tsum + partial[blockIdx.x];
    #pragma unroll
    for (int j = 0; j < 4; ++j) {
        int idx = base + j;
        if (idx < N_NODES) row_start[idx] = excl;
        excl += v[j];
    }
    if (blockIdx.x == 0 && t == 0) row_start[N_NODES] = N_EDGES;
}

__global__ __launch_bounds__(256) void fill_kernel(
    const int* __restrict__ src, const int* __restrict__ dst,
    const int* __restrict__ row_start, int* __restrict__ cur,
    int* __restrict__ adj)
{
    int e = blockIdx.x * blockDim.x + threadIdx.x;
    if (e >= N_EDGES) return;
    int d = dst[e];
    int ofs = atomicAdd(&cur[d], 1);
    adj[row_start[d] + ofs] = src[e];
}

// ---------------- per-layer kernels ----------------

// hsum[n] = in[n] + sum_{s in adj[n]} in[s]; one wave per node, float2/lane
__global__ __launch_bounds__(256) void gather_kernel(
    const float* __restrict__ in, const int* __restrict__ row_start,
    const int* __restrict__ adj, float* __restrict__ out)
{
    int gid = blockIdx.x * blockDim.x + threadIdx.x;
    int n = gid >> 6;
    int lane = gid & 63;
    if (n >= N_NODES) return;
    float2 acc = ((const float2*)(in + (long)n * CH))[lane];
    int beg = row_start[n];
    int end = row_start[n + 1];
    for (int i = beg; i < end; ++i) {
        int s = adj[i];
        float2 v = ((const float2*)(in + (long)s * CH))[lane];
        acc.x += v.x;
        acc.y += v.y;
    }
    ((float2*)(out + (long)n * CH))[lane] = acc;
}

// Fused GIN MLP, in place: h = relu( relu(bn(h @ W1 + b1)) @ W2 + b2 )
// 64-row tile per block, 256 threads, 4x8 register tile per thread.
__global__ __launch_bounds__(256) void mlp_kernel(
    float* __restrict__ h,
    const float* __restrict__ W1, const float* __restrict__ b1,
    const float* __restrict__ gamma, const float* __restrict__ beta,
    const float* __restrict__ mean, const float* __restrict__ var,
    const float* __restrict__ W2, const float* __restrict__ b2)
{
    __shared__ float a_s[TM * PAD];
    const int tid = threadIdx.x;
    const int tx = tid & 15;   // 16 col-groups of 8
    const int ty = tid >> 4;   // 16 row-groups of 4
    const long base = (long)blockIdx.x * TM * CH;

    // stage tile (scalar LDS writes into padded layout)
    for (int i = tid; i < TM * CH / 4; i += 256) {
        float4 hv = ((const float4*)h)[base / 4 + i];
        int r = i >> 5;            // 32 float4 per row
        int c = (i & 31) << 2;
        float* dp = &a_s[r * PAD + c];
        dp[0] = hv.x; dp[1] = hv.y; dp[2] = hv.z; dp[3] = hv.w;
    }

    // fold bias+BN into per-column scale/shift for this thread's 8 columns
    float A[8], Bc[8], b2c[8];
    #pragma unroll
    for (int j = 0; j < 8; ++j) {
        int c = tx * 8 + j;
        float rs = rsqrtf(var[c] + BN_EPS);
        float sc = rs * gamma[c];
        A[j] = sc;
        Bc[j] = (b1[c] - mean[c]) * sc + beta[c];
        b2c[j] = b2[c];
    }

    __syncthreads();

    float acc[4][8];
    #pragma unroll
    for (int i = 0; i < 4; ++i)
        #pragma unroll
        for (int j = 0; j < 8; ++j) acc[i][j] = 0.f;

    // GEMM1: t = a @ W1
    for (int k = 0; k < CH; ++k) {
        float4 w0 = *(const float4*)&W1[k * CH + tx * 8];
        float4 w1v = *(const float4*)&W1[k * CH + tx * 8 + 4];
        float a0 = a_s[(ty * 4 + 0) * PAD + k];
        float a1 = a_s[(ty * 4 + 1) * PAD + k];
        float a2 = a_s[(ty * 4 + 2) * PAD + k];
        float a3 = a_s[(ty * 4 + 3) * PAD + k];
        float wv[8] = {w0.x, w0.y, w0.z, w0.w, w1v.x, w1v.y, w1v.z, w1v.w};
        float av[4] = {a0, a1, a2, a3};
        #pragma unroll
        for (int i = 0; i < 4; ++i)
            #pragma unroll
            for (int j = 0; j < 8; ++j)
                acc[i][j] = fmaf(av[i], wv[j], acc[i][j]);
    }

    __syncthreads();  // everyone done reading a_s

    // BN + ReLU, write t back into a_s
    #pragma unroll
    for (int i = 0; i < 4; ++i) {
        int r = ty * 4 + i;
        #pragma unroll
        for (int j = 0; j < 8; ++j) {
            float t = fmaf(acc[i][j], A[j], Bc[j]);
            a_s[r * PAD + tx * 8 + j] = fmaxf(t, 0.f);
        }
    }
    __syncthreads();

    #pragma unroll
    for (int i = 0; i < 4; ++i)
        #pragma unroll
        for (int j = 0; j < 8; ++j) acc[i][j] = 0.f;

    // GEMM2: out = t @ W2
    for (int k = 0; k < CH; ++k) {
        float4 w0 = *(const float4*)&W2[k * CH + tx * 8];
        float4 w1v = *(const float4*)&W2[k * CH + tx * 8 + 4];
        float a0 = a_s[(ty * 4 + 0) * PAD + k];
        float a1 = a_s[(ty * 4 + 1) * PAD + k];
        float a2 = a_s[(ty * 4 + 2) * PAD + k];
        float a3 = a_s[(ty * 4 + 3) * PAD + k];
        float wv[8] = {w0.x, w0.y, w0.z, w0.w, w1v.x, w1v.y, w1v.z, w1v.w};
        float av[4] = {a0, a1, a2, a3};
        #pragma unroll
        for (int i = 0; i < 4; ++i)
            #pragma unroll
            for (int j = 0; j < 8; ++j)
                acc[i][j] = fmaf(av[i], wv[j], acc[i][j]);
    }

    // bias + ReLU, store in place
    #pragma unroll
    for (int i = 0; i < 4; ++i) {
        long row = (long)blockIdx.x * TM + ty * 4 + i;
        float4 o0, o1;
        o0.x = fmaxf(acc[i][0] + b2c[0], 0.f);
        o0.y = fmaxf(acc[i][1] + b2c[1], 0.f);
        o0.z = fmaxf(acc[i][2] + b2c[2], 0.f);
        o0.w = fmaxf(acc[i][3] + b2c[3], 0.f);
        o1.x = fmaxf(acc[i][4] + b2c[4], 0.f);
        o1.y = fmaxf(acc[i][5] + b2c[5], 0.f);
        o1.z = fmaxf(acc[i][6] + b2c[6], 0.f);
        o1.w = fmaxf(acc[i][7] + b2c[7], 0.f);
        ((float4*)h)[row * (CH / 4) + tx * 2] = o0;
        ((float4*)h)[row * (CH / 4) + tx * 2 + 1] = o1;
    }
}

__global__ void init_out(float* __restrict__ out, const float* __restrict__ lin_b) {
    int i = blockIdx.x * blockDim.x + threadIdx.x;
    if (i < N_GRAPHS) out[i] = lin_b[0];
}

// out[batch[n]] += dot(h[n], lin_w); one wave per node
__global__ __launch_bounds__(256) void pool_kernel(
    const float* __restrict__ h, const int* __restrict__ batch,
    const float* __restrict__ lin_w, float* __restrict__ out)
{
    int gid = blockIdx.x * blockDim.x + threadIdx.x;
    int n = gid >> 6;
    int lane = gid & 63;
    if (n >= N_NODES) return;
    float2 v = ((const float2*)(h + (long)n * CH))[lane];
    float2 w = ((const float2*)lin_w)[lane];
    float s = v.x * w.x + v.y * w.y;
    #pragma unroll
    for (int off = 32; off > 0; off >>= 1) s += __shfl_down(s, off);
    if (lane == 0) atomicAdd(&out[batch[n]], s);
}

extern "C" void kernel_launch(void* const* d_in, const int* in_sizes, int n_in,
                              void* d_out, int out_size, void* d_ws, size_t ws_size,
                              hipStream_t stream) {
    const float* x     = (const float*)d_in[0];
    const int*   ei    = (const int*)d_in[1];
    const int*   batch = (const int*)d_in[2];
    const float* lin_w = (const float*)d_in[3];
    const float* lin_b = (const float*)d_in[4];
    const float* P[3][8];
    for (int l = 0; l < 3; ++l)
        for (int j = 0; j < 8; ++j)
            P[l][j] = (const float*)d_in[5 + l * 8 + j];

    const int* src = ei;            // edge_index[0]
    const int* dst = ei + N_EDGES;  // edge_index[1]

    // workspace layout
    float* buf0 = (float*)d_ws;
    float* buf1 = buf0 + (size_t)N_NODES * CH;
    int* deg       = (int*)(buf1 + (size_t)N_NODES * CH);  // also reused as fill cursor
    int* row_start = deg + N_NODES;                        // N_NODES + 1
    int* adj       = row_start + N_NODES + 1;              // N_EDGES
    int* partial   = adj + N_EDGES;                        // SCAN_NB

    // ---- CSR build (per launch; same work every call) ----
    hipMemsetAsync(deg, 0, N_NODES * sizeof(int), stream);
    count_kernel<<<(N_EDGES + 255) / 256, 256, 0, stream>>>(dst, deg);
    block_sums_kernel<<<SCAN_NB, 256, 0, stream>>>(deg, partial);
    scan_partial_kernel<<<1, 64, 0, stream>>>(partial);
    scan_final_kernel<<<SCAN_NB, 256, 0, stream>>>(deg, partial, row_start);
    hipMemsetAsync(deg, 0, N_NODES * sizeof(int), stream);  // reuse as cursor
    fill_kernel<<<(N_EDGES + 255) / 256, 256, 0, stream>>>(src, dst, row_start, deg, adj);

    // ---- 3 GIN layers: gather (ping-pong) + in-place MLP ----
    const float* in_l[3]  = {x,    buf0, buf1};
    float*       gout[3]  = {buf0, buf1, buf0};

    for (int l = 0; l < 3; ++l) {
        gather_kernel<<<(N_NODES * 64) / 256, 256, 0, stream>>>(
            in_l[l], row_start, adj, gout[l]);
        mlp_kernel<<<N_NODES / TM, 256, 0, stream>>>(
            gout[l],
            P[l][0], P[l][1], P[l][2], P[l][3], P[l][4], P[l][5], P[l][6], P[l][7]);
    }

    // ---- pool + final linear (OUT_CH == 1) ----
    init_out<<<(N_GRAPHS + 255) / 256, 256, 0, stream>>>((float*)d_out, lin_b);
    pool_kernel<<<(N_NODES * 64) / 256, 256, 0, stream>>>(buf0, batch, lin_w, (float*)d_out);
}

// Round 3
// 1154.984 us; speedup vs baseline: 1.7486x; 1.0869x over previous
//
#include <hip/hip_runtime.h>

#define N_NODES 200000
#define N_EDGES 400000
#define CH 128
#define N_GRAPHS 8192
#define BN_EPS 1e-5f

#define TM 64
#define SCAN_NB ((N_NODES + 1023) / 1024)   // 196 scan blocks

typedef __attribute__((ext_vector_type(8))) short bf16x8;
typedef __attribute__((ext_vector_type(4))) float f32x4;

__device__ __forceinline__ short f2bf(float f) {
    unsigned u = __builtin_bit_cast(unsigned, f);
    u = (u + 0x7FFF + ((u >> 16) & 1)) >> 16;   // RNE
    return (short)u;
}
__device__ __forceinline__ float bf2f(short h) {
    unsigned u = ((unsigned)(unsigned short)h) << 16;
    return __builtin_bit_cast(float, u);
}
// LDS element offset, 16B-unit XOR swizzle (conflict-free b128 column reads)
__device__ __forceinline__ int lds_off(int row, int k) {
    return row * CH + ((((k >> 3) ^ (row & 7)) << 3) | (k & 7));
}

// ---------------- CSR build ----------------

__global__ __launch_bounds__(256) void count_kernel(
    const int* __restrict__ dst, int* __restrict__ deg)
{
    int e = blockIdx.x * blockDim.x + threadIdx.x;
    if (e < N_EDGES) atomicAdd(&deg[dst[e]], 1);
}

__global__ __launch_bounds__(256) void block_sums_kernel(
    const int* __restrict__ deg, int* __restrict__ partial)
{
    __shared__ int s[256];
    int t = threadIdx.x;
    int base = blockIdx.x * 1024 + t * 4;
    int v = 0;
    #pragma unroll
    for (int j = 0; j < 4; ++j) {
        int idx = base + j;
        if (idx < N_NODES) v += deg[idx];
    }
    s[t] = v;
    __syncthreads();
    for (int off = 128; off > 0; off >>= 1) {
        if (t < off) s[t] += s[t + off];
        __syncthreads();
    }
    if (t == 0) partial[blockIdx.x] = s[0];
}

__global__ void scan_partial_kernel(int* __restrict__ partial)
{
    if (threadIdx.x == 0) {
        int run = 0;
        for (int b = 0; b < SCAN_NB; ++b) {
            int v = partial[b];
            partial[b] = run;
            run += v;
        }
    }
}

__global__ __launch_bounds__(256) void scan_final_kernel(
    const int* __restrict__ deg, const int* __restrict__ partial,
    int* __restrict__ row_start)
{
    __shared__ int s[256];
    int t = threadIdx.x;
    int base = blockIdx.x * 1024 + t * 4;
    int v[4];
    int tsum = 0;
    #pragma unroll
    for (int j = 0; j < 4; ++j) {
        int idx = base + j;
        v[j] = (idx < N_NODES) ? deg[idx] : 0;
        tsum += v[j];
    }
    s[t] = tsum;
    __syncthreads();
    for (int off = 1; off < 256; off <<= 1) {
        int x = (t >= off) ? s[t - off] : 0;
        __syncthreads();
        s[t] += x;
        __syncthreads();
    }
    int excl = s[t] - tsum + partial[blockIdx.x];
    #pragma unroll
    for (int j = 0; j < 4; ++j) {
        int idx = base + j;
        if (idx < N_NODES) row_start[idx] = excl;
        excl += v[j];
    }
    if (blockIdx.x == 0 && t == 0) row_start[N_NODES] = N_EDGES;
}

__global__ __launch_bounds__(256) void fill_kernel(
    const int* __restrict__ src, const int* __restrict__ dst,
    const int* __restrict__ row_start, int* __restrict__ cur,
    int* __restrict__ adj)
{
    int e = blockIdx.x * blockDim.x + threadIdx.x;
    if (e >= N_EDGES) return;
    int d = dst[e];
    int ofs = atomicAdd(&cur[d], 1);
    adj[row_start[d] + ofs] = src[e];
}

// ---------------- weight prep: transpose + bf16 hi/lo split + BN fold ----------------
// grid: 128 blocks x 256 (idx 0..32767); idx<16384 -> W1, else W2
__global__ __launch_bounds__(256) void prep_kernel(
    const float* __restrict__ W1, const float* __restrict__ W2,
    const float* __restrict__ b1, const float* __restrict__ gamma,
    const float* __restrict__ beta, const float* __restrict__ mean,
    const float* __restrict__ var,
    short* __restrict__ w1t_hi, short* __restrict__ w1t_lo,
    short* __restrict__ w2t_hi, short* __restrict__ w2t_lo,
    float* __restrict__ bnA, float* __restrict__ bnB)
{
    int idx = blockIdx.x * 256 + threadIdx.x;
    const float* W = (idx < 16384) ? W1 : W2;
    short* th = (idx < 16384) ? w1t_hi : w2t_hi;
    short* tl = (idx < 16384) ? w1t_lo : w2t_lo;
    int e = idx & 16383;
    int c = e >> 7, k = e & 127;
    float w = W[k * CH + c];
    short hi = f2bf(w);
    th[c * CH + k] = hi;
    tl[c * CH + k] = f2bf(w - bf2f(hi));
    if (idx < CH) {
        float sc = rsqrtf(var[idx] + BN_EPS) * gamma[idx];
        bnA[idx] = sc;
        bnB[idx] = (b1[idx] - mean[idx]) * sc + beta[idx];
    }
}

// ---------------- per-layer kernels ----------------

// hsum[n] = in[n] + sum_{s in adj[n]} in[s]; one wave per node, float2/lane
__global__ __launch_bounds__(256) void gather_kernel(
    const float* __restrict__ in, const int* __restrict__ row_start,
    const int* __restrict__ adj, float* __restrict__ out)
{
    int gid = blockIdx.x * blockDim.x + threadIdx.x;
    int n = gid >> 6;
    int lane = gid & 63;
    if (n >= N_NODES) return;
    float2 acc = ((const float2*)(in + (long)n * CH))[lane];
    int beg = row_start[n];
    int end = row_start[n + 1];
    for (int i = beg; i < end; ++i) {
        int s = adj[i];
        float2 v = ((const float2*)(in + (long)s * CH))[lane];
        acc.x += v.x;
        acc.y += v.y;
    }
    ((float2*)(out + (long)n * CH))[lane] = acc;
}

// Fused GIN MLP via MFMA bf16x3, in place:
//   h = relu( relu(bn(h @ W1 + b1)) @ W2 + b2 )
// 64 rows/block, 4 waves, each wave owns 16 rows x 128 cols.
__global__ __launch_bounds__(256) void mlp_mfma(
    float* __restrict__ h,
    const short* __restrict__ w1t_hi, const short* __restrict__ w1t_lo,
    const short* __restrict__ w2t_hi, const short* __restrict__ w2t_lo,
    const float* __restrict__ bnA, const float* __restrict__ bnB,
    const float* __restrict__ b2)
{
    __shared__ short t_hi[TM * CH];
    __shared__ short t_lo[TM * CH];
    const int tid = threadIdx.x;
    const int w  = tid >> 6;
    const int l  = tid & 63;
    const int lr = l & 15;     // A-row / B-col / C-col within 16-tile
    const int lk = l >> 4;     // k-group (8 elems each)
    const long rowbase = (long)blockIdx.x * TM + w * 16;

    // ---- GEMM1: A straight from global f32 (hi/lo split in-register) ----
    bf16x8 ah[4], al[4];
    #pragma unroll
    for (int ks = 0; ks < 4; ++ks) {
        const float* p = h + (rowbase + lr) * CH + ks * 32 + lk * 8;
        float4 f0 = *(const float4*)p;
        float4 f1 = *(const float4*)(p + 4);
        float fv[8] = {f0.x, f0.y, f0.z, f0.w, f1.x, f1.y, f1.z, f1.w};
        #pragma unroll
        for (int j = 0; j < 8; ++j) {
            short hi = f2bf(fv[j]);
            ah[ks][j] = hi;
            al[ks][j] = f2bf(fv[j] - bf2f(hi));
        }
    }

    f32x4 acc[8];
    #pragma unroll
    for (int ct = 0; ct < 8; ++ct) acc[ct] = (f32x4){0.f, 0.f, 0.f, 0.f};

    #pragma unroll
    for (int ct = 0; ct < 8; ++ct) {
        const short* bph = w1t_hi + (ct * 16 + lr) * CH + lk * 8;
        const short* bpl = w1t_lo + (ct * 16 + lr) * CH + lk * 8;
        #pragma unroll
        for (int ks = 0; ks < 4; ++ks) {
            bf16x8 bh = *(const bf16x8*)(bph + ks * 32);
            bf16x8 bl = *(const bf16x8*)(bpl + ks * 32);
            acc[ct] = __builtin_amdgcn_mfma_f32_16x16x32_bf16(ah[ks], bh, acc[ct], 0, 0, 0);
            acc[ct] = __builtin_amdgcn_mfma_f32_16x16x32_bf16(ah[ks], bl, acc[ct], 0, 0, 0);
            acc[ct] = __builtin_amdgcn_mfma_f32_16x16x32_bf16(al[ks], bh, acc[ct], 0, 0, 0);
        }
    }

    // ---- BN + ReLU, C-layout -> swizzled LDS (A-layout source for GEMM2) ----
    // C/D mapping (m89): col = lr, row = lk*4 + i
    #pragma unroll
    for (int ct = 0; ct < 8; ++ct) {
        int col = ct * 16 + lr;
        float sA = bnA[col], sB = bnB[col];
        #pragma unroll
        for (int i = 0; i < 4; ++i) {
            int row = w * 16 + lk * 4 + i;
            float t = fmaf(acc[ct][i], sA, sB);
            t = fmaxf(t, 0.f);
            short hi = f2bf(t);
            t_hi[lds_off(row, col)] = hi;
            t_lo[lds_off(row, col)] = f2bf(t - bf2f(hi));
        }
    }
    __syncthreads();   // cheap; guarantees LDS visibility

    // ---- GEMM2: A from LDS, B = w2t ----
    bf16x8 a2h[4], a2l[4];
    #pragma unroll
    for (int ks = 0; ks < 4; ++ks) {
        int row = w * 16 + lr;
        int k0 = ks * 32 + lk * 8;
        a2h[ks] = *(const bf16x8*)&t_hi[lds_off(row, k0)];
        a2l[ks] = *(const bf16x8*)&t_lo[lds_off(row, k0)];
    }
    #pragma unroll
    for (int ct = 0; ct < 8; ++ct) acc[ct] = (f32x4){0.f, 0.f, 0.f, 0.f};

    #pragma unroll
    for (int ct = 0; ct < 8; ++ct) {
        const short* bph = w2t_hi + (ct * 16 + lr) * CH + lk * 8;
        const short* bpl = w2t_lo + (ct * 16 + lr) * CH + lk * 8;
        #pragma unroll
        for (int ks = 0; ks < 4; ++ks) {
            bf16x8 bh = *(const bf16x8*)(bph + ks * 32);
            bf16x8 bl = *(const bf16x8*)(bpl + ks * 32);
            acc[ct] = __builtin_amdgcn_mfma_f32_16x16x32_bf16(a2h[ks], bh, acc[ct], 0, 0, 0);
            acc[ct] = __builtin_amdgcn_mfma_f32_16x16x32_bf16(a2h[ks], bl, acc[ct], 0, 0, 0);
            acc[ct] = __builtin_amdgcn_mfma_f32_16x16x32_bf16(a2l[ks], bh, acc[ct], 0, 0, 0);
        }
    }

    // ---- bias + ReLU, store in place ----
    #pragma unroll
    for (int ct = 0; ct < 8; ++ct) {
        int col = ct * 16 + lr;
        float bb = b2[col];
        #pragma unroll
        for (int i = 0; i < 4; ++i) {
            long row = rowbase + lk * 4 + i;
            h[row * CH + col] = fmaxf(acc[ct][i] + bb, 0.f);
        }
    }
}

__global__ void init_out(float* __restrict__ out, const float* __restrict__ lin_b) {
    int i = blockIdx.x * blockDim.x + threadIdx.x;
    if (i < N_GRAPHS) out[i] = lin_b[0];
}

// out[batch[n]] += dot(h[n], lin_w); one wave per node
__global__ __launch_bounds__(256) void pool_kernel(
    const float* __restrict__ h, const int* __restrict__ batch,
    const float* __restrict__ lin_w, float* __restrict__ out)
{
    int gid = blockIdx.x * blockDim.x + threadIdx.x;
    int n = gid >> 6;
    int lane = gid & 63;
    if (n >= N_NODES) return;
    float2 v = ((const float2*)(h + (long)n * CH))[lane];
    float2 w = ((const float2*)lin_w)[lane];
    float s = v.x * w.x + v.y * w.y;
    #pragma unroll
    for (int off = 32; off > 0; off >>= 1) s += __shfl_down(s, off);
    if (lane == 0) atomicAdd(&out[batch[n]], s);
}

extern "C" void kernel_launch(void* const* d_in, const int* in_sizes, int n_in,
                              void* d_out, int out_size, void* d_ws, size_t ws_size,
                              hipStream_t stream) {
    const float* x     = (const float*)d_in[0];
    const int*   ei    = (const int*)d_in[1];
    const int*   batch = (const int*)d_in[2];
    const float* lin_w = (const float*)d_in[3];
    const float* lin_b = (const float*)d_in[4];
    const float* P[3][8];
    for (int l = 0; l < 3; ++l)
        for (int j = 0; j < 8; ++j)
            P[l][j] = (const float*)d_in[5 + l * 8 + j];
    // P[l]: 0=w1 1=b1 2=gamma 3=beta 4=mean 5=var 6=w2 7=b2

    const int* src = ei;            // edge_index[0]
    const int* dst = ei + N_EDGES;  // edge_index[1]

    // workspace layout
    float* buf0 = (float*)d_ws;
    float* buf1 = buf0 + (size_t)N_NODES * CH;
    int* deg       = (int*)(buf1 + (size_t)N_NODES * CH);
    int* row_start = deg + N_NODES;
    int* adj       = row_start + N_NODES + 1;
    int* partial   = adj + N_EDGES;
    short* wts     = (short*)(partial + SCAN_NB + 64);
    // per layer: w1t_hi, w1t_lo, w2t_hi, w2t_lo (16384 shorts each) + bnA,bnB (128 floats each)
    short* w1t_hi[3]; short* w1t_lo[3]; short* w2t_hi[3]; short* w2t_lo[3];
    float* bnA[3]; float* bnB[3];
    {
        short* p = wts;
        for (int l = 0; l < 3; ++l) {
            w1t_hi[l] = p; p += 16384;
            w1t_lo[l] = p; p += 16384;
            w2t_hi[l] = p; p += 16384;
            w2t_lo[l] = p; p += 16384;
            bnA[l] = (float*)p; p += 256;   // 128 floats
            bnB[l] = (float*)p; p += 256;
        }
    }

    // ---- weight prep ----
    for (int l = 0; l < 3; ++l)
        prep_kernel<<<128, 256, 0, stream>>>(
            P[l][0], P[l][6], P[l][1], P[l][2], P[l][3], P[l][4], P[l][5],
            w1t_hi[l], w1t_lo[l], w2t_hi[l], w2t_lo[l], bnA[l], bnB[l]);

    // ---- CSR build ----
    hipMemsetAsync(deg, 0, N_NODES * sizeof(int), stream);
    count_kernel<<<(N_EDGES + 255) / 256, 256, 0, stream>>>(dst, deg);
    block_sums_kernel<<<SCAN_NB, 256, 0, stream>>>(deg, partial);
    scan_partial_kernel<<<1, 64, 0, stream>>>(partial);
    scan_final_kernel<<<SCAN_NB, 256, 0, stream>>>(deg, partial, row_start);
    hipMemsetAsync(deg, 0, N_NODES * sizeof(int), stream);  // reuse as cursor
    fill_kernel<<<(N_EDGES + 255) / 256, 256, 0, stream>>>(src, dst, row_start, deg, adj);

    // ---- 3 GIN layers: gather (ping-pong) + in-place MFMA MLP ----
    const float* in_l[3] = {x,    buf0, buf1};
    float*       gout[3] = {buf0, buf1, buf0};

    for (int l = 0; l < 3; ++l) {
        gather_kernel<<<(N_NODES * 64) / 256, 256, 0, stream>>>(
            in_l[l], row_start, adj, gout[l]);
        mlp_mfma<<<N_NODES / TM, 256, 0, stream>>>(
            gout[l],
            w1t_hi[l], w1t_lo[l], w2t_hi[l], w2t_lo[l],
            bnA[l], bnB[l], P[l][7]);
    }

    // ---- pool + final linear (OUT_CH == 1) ----
    init_out<<<(N_GRAPHS + 255) / 256, 256, 0, stream>>>((float*)d_out, lin_b);
    pool_kernel<<<(N_NODES * 64) / 256, 256, 0, stream>>>(buf0, batch, lin_w, (float*)d_out);
}